// Round 10
// baseline (79.209 us; speedup 1.0000x reference)
//
#include <hip/hip_runtime.h>
#include <math.h>

#define Nn 6144
#define FIN 128
#define DMID 128
#define DHID 64
#define NH 4
#define NG 12
#define NB 512
#define ALPHA 0.2f
#define EPSV 1e-9f

typedef __bf16 bf16x8 __attribute__((ext_vector_type(8)));
typedef float f32x4 __attribute__((ext_vector_type(4)));
typedef unsigned short ushort_t;

union BU { bf16x8 v; uint u[4]; uint4 q; };

__device__ __forceinline__ float leaky(float x){ return x > 0.f ? x : ALPHA*x; }
__device__ __forceinline__ float eluf(float x){ return x > 0.f ? x : __expf(x)-1.f; }
__device__ __forceinline__ uint f2bf(float f){
  uint u = __float_as_uint(f);
  return (u + 0x7FFFu + ((u>>16)&1u)) >> 16;
}
__device__ __forceinline__ float wave_max(float v){
  #pragma unroll
  for (int off=32; off; off>>=1) v = fmaxf(v, __shfl_xor(v, off));
  return v;
}
// pack 8 consecutive-k weights W[k0..k0+7][col] (row stride strd) into one B-frag uint4
__device__ __forceinline__ uint4 packW(const float* p, int strd){
  uint4 pk;
  pk.x = f2bf(p[0])      | (f2bf(p[strd])<<16);
  pk.y = f2bf(p[2*strd]) | (f2bf(p[3*strd])<<16);
  pk.z = f2bf(p[4*strd]) | (f2bf(p[5*strd])<<16);
  pk.w = f2bf(p[6*strd]) | (f2bf(p[7*strd])<<16);
  return pk;
}

// ---------- K1: fc1 + ft0 (MFMA, inline weight fragments) + dots + swizzled ftS ----------
// 384 blocks x 256 threads; block b: rows [b*16, b*16+16)
__global__ __launch_bounds__(256) void k_f1(
    const float* __restrict__ x, const float* __restrict__ Wv, const float* __restrict__ bv,
    const float* __restrict__ W0, const float* __restrict__ al0, const float* __restrict__ ar0,
    ushort_t* __restrict__ ftS, float* __restrict__ a1arr, float* __restrict__ a2arr,
    float* __restrict__ pmax0, int* __restrict__ cnt){
  int b = blockIdx.x; int i0 = b*16;
  int t = threadIdx.x, lane = t&63, w = t>>6;
  int row = lane&15, kg = lane>>4;
  if (b == 0 && t < NG) cnt[t] = 0;   // reset MLP tickets every launch
  __shared__ ushort_t xs[16][136];
  __shared__ ushort_t hts[16][136];
  __shared__ ushort_t fts[16][264];
  {
    const float* xp = x + (size_t)i0*FIN + t*8;
    float4 f0 = *reinterpret_cast<const float4*>(xp);
    float4 f1 = *reinterpret_cast<const float4*>(xp+4);
    uint4 pk;
    pk.x = f2bf(f0.x)|(f2bf(f0.y)<<16); pk.y = f2bf(f0.z)|(f2bf(f0.w)<<16);
    pk.z = f2bf(f1.x)|(f2bf(f1.y)<<16); pk.w = f2bf(f1.z)|(f2bf(f1.w)<<16);
    *reinterpret_cast<uint4*>(&xs[t>>4][(t&15)*8]) = pk;
  }
  __syncthreads();
  // fc1: h = relu(x@Wv+bv); wave w -> n-tiles 2w, 2w+1
  {
    f32x4 acc2[2] = {{0,0,0,0},{0,0,0,0}};
    #pragma unroll
    for (int kt=0; kt<4; ++kt){
      bf16x8 aF = *reinterpret_cast<bf16x8*>(&xs[row][kt*32 + kg*8]);
      #pragma unroll
      for (int e2=0; e2<2; ++e2){
        int nt = w*2+e2;
        BU B;
        B.q = packW(Wv + (size_t)(kt*32 + (lane>>4)*8)*DMID + nt*16 + (lane&15), DMID);
        acc2[e2] = __builtin_amdgcn_mfma_f32_16x16x32_bf16(aF, B.v, acc2[e2], 0, 0, 0);
      }
    }
    #pragma unroll
    for (int e2=0; e2<2; ++e2){
      int nt = w*2+e2;
      float bvv = bv[nt*16+row];
      #pragma unroll
      for (int reg=0; reg<4; ++reg){
        float v = fmaxf(acc2[e2][reg]+bvv, 0.f);
        hts[kg*4+reg][nt*16+row] = (ushort_t)f2bf(v);
      }
    }
  }
  __syncthreads();
  // ft0: head = w; n-tiles 0..3 within head
  f32x4 acc4[4] = {{0,0,0,0},{0,0,0,0},{0,0,0,0},{0,0,0,0}};
  #pragma unroll
  for (int kt=0; kt<4; ++kt){
    bf16x8 aF = *reinterpret_cast<bf16x8*>(&hts[row][kt*32 + kg*8]);
    #pragma unroll
    for (int nt=0; nt<4; ++nt){
      BU B;
      B.q = packW(W0 + (size_t)w*DMID*DHID + (size_t)(kt*32 + (lane>>4)*8)*DHID
                     + nt*16 + (lane&15), DHID);
      acc4[nt] = __builtin_amdgcn_mfma_f32_16x16x32_bf16(aF, B.v, acc4[nt], 0, 0, 0);
    }
  }
  // dots on C-fragments
  {
    float alv[4], arv[4];
    #pragma unroll
    for (int nt=0; nt<4; ++nt){ alv[nt] = al0[w*DHID+nt*16+row]; arv[nt] = ar0[w*DHID+nt*16+row]; }
    float s1[4]={0,0,0,0}, s2[4]={0,0,0,0};
    #pragma unroll
    for (int nt=0; nt<4; ++nt)
      #pragma unroll
      for (int reg=0; reg<4; ++reg){
        s1[reg] += acc4[nt][reg]*alv[nt];
        s2[reg] += acc4[nt][reg]*arv[nt];
      }
    #pragma unroll
    for (int off=1; off<16; off<<=1)
      #pragma unroll
      for (int reg=0; reg<4; ++reg){
        s1[reg] += __shfl_xor(s1[reg], off);
        s2[reg] += __shfl_xor(s2[reg], off);
      }
    if (row==0){
      #pragma unroll
      for (int reg=0; reg<4; ++reg){
        a1arr[w*Nn + i0 + kg*4+reg] = s1[reg];
        a2arr[w*Nn + i0 + kg*4+reg] = s2[reg];
      }
    }
    float mm = fmaxf(fmaxf(s2[0],s2[1]), fmaxf(s2[2],s2[3]));
    mm = fmaxf(mm, __shfl_xor(mm,16));
    mm = fmaxf(mm, __shfl_xor(mm,32));
    if (lane==0) pmax0[w*384 + b] = mm;
  }
  // fts LDS
  #pragma unroll
  for (int nt=0; nt<4; ++nt)
    #pragma unroll
    for (int reg=0; reg<4; ++reg)
      fts[kg*4+reg][w*DHID + nt*16+row] = (ushort_t)f2bf(acc4[nt][reg]);
  __syncthreads();
  // write swizzled ftS: thread t <-> channel
  {
    int ch = t, hd2 = ch>>6, ct = (ch>>4)&3, c = ch&15;
    int g = b>>5, ktj = (b&31)>>1, half = b&1;
    ushort_t v[16];
    #pragma unroll
    for (int i=0; i<16; ++i) v[i] = fts[i][ch];
    uint4 p0, p1;
    p0.x=(uint)v[0]|((uint)v[1]<<16);  p0.y=(uint)v[2]|((uint)v[3]<<16);
    p0.z=(uint)v[4]|((uint)v[5]<<16);  p0.w=(uint)v[6]|((uint)v[7]<<16);
    p1.x=(uint)v[8]|((uint)v[9]<<16);  p1.y=(uint)v[10]|((uint)v[11]<<16);
    p1.z=(uint)v[12]|((uint)v[13]<<16);p1.w=(uint)v[14]|((uint)v[15]<<16);
    size_t base = (((size_t)(g*4+hd2)*16 + ktj)*4 + ct)*512;
    *reinterpret_cast<uint4*>(ftS + base + ((half*2+0)*16+c)*8) = p0;
    *reinterpret_cast<uint4*>(ftS + base + ((half*2+1)*16+c)*8) = p1;
  }
}

// ---------- K2: fused attention-0 (4 heads x 2 j-halves) + fcf (inline Wf frags) ----------
__global__ __launch_bounds__(512) void k_attn0fcf(
    const ushort_t* __restrict__ ftS, const float* __restrict__ a1arr,
    const float* __restrict__ a2arr, const float* __restrict__ pmax0,
    const float* __restrict__ mask, const float* __restrict__ Wf,
    const float* __restrict__ alf, const float* __restrict__ arf,
    ushort_t* __restrict__ ftfS, float* __restrict__ a1f, float* __restrict__ a2f,
    float* __restrict__ pmaxf){
  int b = blockIdx.x;            // 384 = g*32 + it
  int g = b>>5, it = b&31;
  int i0 = g*NB + it*16, jbase = g*NB;
  int t = threadIdx.x, lane = t&63, w = t>>6;
  int hd = w>>1, jh = w&1;
  int row = lane&15, kg = lane>>4;

  __shared__ float aacc[8][4][64][4];    // 32 KB
  __shared__ float ad[8][16];
  __shared__ ushort_t h1s[16][264];      // 8.4 KB
  __shared__ ushort_t fts[16][136];      // 4.3 KB
  __shared__ float dpA[8][16], dpB[8][16];

  // ---- phase A: scores + PV (head hd, j-half jh) ----
  {
    float pm = (lane < 32) ? pmax0[hd*384 + g*32 + lane] : -INFINITY;
    float mxv = wave_max(pm);
    float a1v = a1arr[hd*Nn + i0 + row];
    float mv = leaky(a1v + mxv);
    f32x4 acc[4] = {{0,0,0,0},{0,0,0,0},{0,0,0,0},{0,0,0,0}};
    float dsum = 0.f;
    const float* mrow = mask + (size_t)(i0+row)*Nn;
    size_t fbase = ((size_t)(g*4+hd)*16*4)*512;
    #pragma unroll 4
    for (int c8=0; c8<8; ++c8){
      int kt = jh*8 + c8;
      int jc = jbase + kt*32 + kg*8;
      float4 mk0 = *reinterpret_cast<const float4*>(mrow + jc);
      float4 mk1 = *reinterpret_cast<const float4*>(mrow + jc + 4);
      float4 a20 = *reinterpret_cast<const float4*>(a2arr + hd*Nn + jc);
      float4 a21 = *reinterpret_cast<const float4*>(a2arr + hd*Nn + jc + 4);
      float a2l[8] = {a20.x,a20.y,a20.z,a20.w,a21.x,a21.y,a21.z,a21.w};
      float mkl[8] = {mk0.x,mk0.y,mk0.z,mk0.w,mk1.x,mk1.y,mk1.z,mk1.w};
      float wv[8];
      #pragma unroll
      for (int e=0;e<8;++e){
        float p = __expf(leaky(a1v + a2l[e]) - mv) * mkl[e];
        wv[e] = p; dsum += p;
      }
      BU A;
      #pragma unroll
      for (int q=0;q<4;++q) A.u[q] = f2bf(wv[2*q]) | (f2bf(wv[2*q+1])<<16);
      #pragma unroll
      for (int ct=0; ct<4; ++ct){
        BU B; B.q = *reinterpret_cast<const uint4*>(ftS + fbase + (size_t)(kt*4+ct)*512 + lane*8);
        acc[ct] = __builtin_amdgcn_mfma_f32_16x16x32_bf16(A.v, B.v, acc[ct], 0, 0, 0);
      }
    }
    dsum += __shfl_xor(dsum, 16);
    dsum += __shfl_xor(dsum, 32);
    if (lane < 16) ad[w][lane] = dsum;
    #pragma unroll
    for (int ct=0; ct<4; ++ct)
      *reinterpret_cast<float4*>(&aacc[w][ct][lane][0]) = (float4){acc[ct][0],acc[ct][1],acc[ct][2],acc[ct][3]};
  }
  __syncthreads();
  // ---- phase B: combine j-halves, ELU, write h1 tile (bf16 LDS) ----
  {
    int w0 = hd*2, w1 = hd*2+1;
    float dr[4];
    #pragma unroll
    for (int reg=0; reg<4; ++reg) dr[reg] = ad[w0][kg*4+reg] + ad[w1][kg*4+reg] + EPSV;
    #pragma unroll
    for (int ci=0; ci<2; ++ci){
      int ct = jh*2+ci;
      float4 A0 = *reinterpret_cast<float4*>(&aacc[w0][ct][lane][0]);
      float4 A1 = *reinterpret_cast<float4*>(&aacc[w1][ct][lane][0]);
      float tot[4] = {A0.x+A1.x, A0.y+A1.y, A0.z+A1.z, A0.w+A1.w};
      #pragma unroll
      for (int reg=0; reg<4; ++reg){
        float o = eluf(tot[reg]/dr[reg]);
        h1s[kg*4+reg][hd*64 + ct*16 + row] = (ushort_t)f2bf(o);
      }
    }
  }
  __syncthreads();
  // ---- phase C: fcf (wave w -> n-tile w), inline Wf fragments, dots ----
  {
    f32x4 acc2 = {0,0,0,0};
    #pragma unroll
    for (int kt=0; kt<8; ++kt){
      bf16x8 aF = *reinterpret_cast<bf16x8*>(&h1s[row][kt*32 + kg*8]);
      BU B;
      B.q = packW(Wf + (size_t)(kt*32 + (lane>>4)*8)*DMID + w*16 + (lane&15), DMID);
      acc2 = __builtin_amdgcn_mfma_f32_16x16x32_bf16(aF, B.v, acc2, 0, 0, 0);
    }
    float alv = alf[w*16+row], arv = arf[w*16+row];
    float s1[4], s2[4];
    #pragma unroll
    for (int reg=0; reg<4; ++reg){
      s1[reg] = acc2[reg]*alv;
      s2[reg] = acc2[reg]*arv;
      fts[kg*4+reg][w*16+row] = (ushort_t)f2bf(acc2[reg]);
    }
    #pragma unroll
    for (int off=1; off<16; off<<=1)
      #pragma unroll
      for (int reg=0; reg<4; ++reg){
        s1[reg] += __shfl_xor(s1[reg], off);
        s2[reg] += __shfl_xor(s2[reg], off);
      }
    if (row==0){
      #pragma unroll
      for (int reg=0; reg<4; ++reg){ dpA[w][kg*4+reg]=s1[reg]; dpB[w][kg*4+reg]=s2[reg]; }
    }
  }
  __syncthreads();
  if (t < 16){
    float v1=0.f, v2=0.f;
    #pragma unroll
    for (int q=0; q<8; ++q){ v1 += dpA[q][t]; v2 += dpB[q][t]; }
    a1f[i0+t] = v1; a2f[i0+t] = v2;
    float m = v2;
    #pragma unroll
    for (int off=1; off<16; off<<=1) m = fmaxf(m, __shfl_xor(m, off));
    if (t==0) pmaxf[b] = m;
  }
  // ---- swizzled ftfS write (first 256 threads) ----
  if (t < 256){
    int ch = t>>1, half8 = t&1;
    int ct = ch>>4, c = ch&15;
    int gg = b>>5, ktj = (b&31)>>1, half = b&1;
    ushort_t v[8];
    #pragma unroll
    for (int i=0; i<8; ++i) v[i] = fts[half8*8+i][ch];
    uint4 pk;
    pk.x=(uint)v[0]|((uint)v[1]<<16); pk.y=(uint)v[2]|((uint)v[3]<<16);
    pk.z=(uint)v[4]|((uint)v[5]<<16); pk.w=(uint)v[6]|((uint)v[7]<<16);
    int kslot = half*2 + half8;
    size_t base = ((size_t)(gg*16+ktj)*8 + ct)*512;
    *reinterpret_cast<uint4*>(ftfS + base + (kslot*16+c)*8) = pk;
  }
}

// ---------- K3: final attention (4-way j-split) + pool partials + per-graph winner MLP ----------
__global__ __launch_bounds__(256) void k_attnf(
    const ushort_t* __restrict__ ftfS, const float* __restrict__ a1f,
    const float* __restrict__ a2f, const float* __restrict__ pmaxf,
    const float* __restrict__ mask,
    const float* __restrict__ W1, const float* __restrict__ b1,
    const float* __restrict__ W2, const float* __restrict__ b2,
    float* __restrict__ ppart, int* __restrict__ cnt, float* __restrict__ out){
  int b = blockIdx.x;             // 384: g, it
  int g = b>>5, it = b&31;
  int i0 = g*NB + it*16, jbase = g*NB;
  int t = threadIdx.x, lane = t&63, w = t>>6;
  int row = lane&15, kg = lane>>4;
  __shared__ float s_acc[4][8][64][4];   // 32 KB
  __shared__ float s_d[4][16];
  __shared__ float red[2][DMID];
  __shared__ float ps[DMID], ts[DMID];
  __shared__ float p4[2][16];
  __shared__ int flag;
  {
    float pm = (lane < 32) ? pmaxf[g*32 + lane] : -INFINITY;
    float mxv = wave_max(pm);
    float a1v = a1f[i0+row];
    float mv = leaky(a1v + mxv);
    f32x4 acc[8];
    #pragma unroll
    for (int ct=0; ct<8; ++ct) acc[ct] = (f32x4){0,0,0,0};
    float dsum = 0.f;
    const float* mrow = mask + (size_t)(i0+row)*Nn;
    #pragma unroll
    for (int c4=0; c4<4; ++c4){
      int kt = w*4 + c4;
      int jc = jbase + kt*32 + kg*8;
      float4 mk0 = *reinterpret_cast<const float4*>(mrow + jc);
      float4 mk1 = *reinterpret_cast<const float4*>(mrow + jc + 4);
      float4 a20 = *reinterpret_cast<const float4*>(a2f + jc);
      float4 a21 = *reinterpret_cast<const float4*>(a2f + jc + 4);
      float a2l[8] = {a20.x,a20.y,a20.z,a20.w,a21.x,a21.y,a21.z,a21.w};
      float mkl[8] = {mk0.x,mk0.y,mk0.z,mk0.w,mk1.x,mk1.y,mk1.z,mk1.w};
      float wv[8];
      #pragma unroll
      for (int e=0;e<8;++e){
        float p = __expf(leaky(a1v + a2l[e]) - mv) * mkl[e];
        wv[e] = p; dsum += p;
      }
      BU A;
      #pragma unroll
      for (int q=0;q<4;++q) A.u[q] = f2bf(wv[2*q]) | (f2bf(wv[2*q+1])<<16);
      #pragma unroll
      for (int ct=0; ct<8; ++ct){
        BU B; B.q = *reinterpret_cast<const uint4*>(ftfS + ((size_t)(g*16+kt)*8 + ct)*512 + lane*8);
        acc[ct] = __builtin_amdgcn_mfma_f32_16x16x32_bf16(A.v, B.v, acc[ct], 0, 0, 0);
      }
    }
    dsum += __shfl_xor(dsum, 16);
    dsum += __shfl_xor(dsum, 32);
    if (lane < 16) s_d[w][lane] = dsum;
    #pragma unroll
    for (int ct=0; ct<8; ++ct)
      *reinterpret_cast<float4*>(&s_acc[w][ct][lane][0]) = (float4){acc[ct][0],acc[ct][1],acc[ct][2],acc[ct][3]};
  }
  __syncthreads();
  {
    float dr[4];
    #pragma unroll
    for (int reg=0; reg<4; ++reg)
      dr[reg] = s_d[0][kg*4+reg] + s_d[1][kg*4+reg] + s_d[2][kg*4+reg] + s_d[3][kg*4+reg] + EPSV;
    #pragma unroll
    for (int ci=0; ci<2; ++ci){
      int ct = w*2 + ci;
      float4 A0 = *reinterpret_cast<float4*>(&s_acc[0][ct][lane][0]);
      float4 A1 = *reinterpret_cast<float4*>(&s_acc[1][ct][lane][0]);
      float4 A2 = *reinterpret_cast<float4*>(&s_acc[2][ct][lane][0]);
      float4 A3 = *reinterpret_cast<float4*>(&s_acc[3][ct][lane][0]);
      float tot[4] = {A0.x+A1.x+A2.x+A3.x, A0.y+A1.y+A2.y+A3.y,
                      A0.z+A1.z+A2.z+A3.z, A0.w+A1.w+A2.w+A3.w};
      float psum = 0.f;
      #pragma unroll
      for (int reg=0; reg<4; ++reg) psum += eluf(tot[reg]/dr[reg]);
      psum += __shfl_xor(psum, 16);
      psum += __shfl_xor(psum, 32);
      if (lane < 16) ppart[(size_t)b*DMID + ct*16 + lane] = psum;
    }
  }
  // ---- per-graph ticket; last block of graph reduces + runs MLP ----
  __threadfence();
  __syncthreads();
  if (t == 0){
    int old = atomicAdd(&cnt[g], 1);
    flag = (old == 31) ? 1 : 0;
  }
  __syncthreads();
  if (flag){
    __threadfence();   // acquire: see all graph-g ppart writes
    {
      int part = t>>7, col = t&127;     // 2 parts x 16 itiles
      float s = 0.f;
      #pragma unroll
      for (int q=0; q<16; ++q) s += ppart[(size_t)(g*32 + part*16 + q)*DMID + col];
      red[part][col] = s;
    }
    __syncthreads();
    if (t < DMID) ps[t] = red[0][t] + red[1][t];
    __syncthreads();
    {
      int col = t&127, half = t>>7;
      float accv = 0.f;
      #pragma unroll 8
      for (int k=half*64; k<half*64+64; ++k) accv += ps[k]*W1[k*DMID+col];
      red[half][col] = accv;
    }
    __syncthreads();
    if (t < DMID) ts[t] = fmaxf(red[0][t] + red[1][t] + b1[t], 0.f);
    __syncthreads();
    if (t < 32){
      int col = t&15, half = t>>4;
      float accv = 0.f;
      #pragma unroll 8
      for (int k=half*64; k<half*64+64; ++k) accv += ts[k]*W2[k*16+col];
      p4[half][col] = accv;
    }
    __syncthreads();
    if (t < 16) out[g*16+t] = p4[0][t] + p4[1][t] + b2[t];
  }
}

extern "C" void kernel_launch(void* const* d_in, const int* in_sizes, int n_in,
                              void* d_out, int out_size, void* d_ws, size_t ws_size,
                              hipStream_t stream) {
  const float* x    = (const float*)d_in[0];
  const float* mask = (const float*)d_in[1];
  const float* Wv   = (const float*)d_in[3];
  const float* bv   = (const float*)d_in[4];
  const float* W0   = (const float*)d_in[5];
  const float* al0  = (const float*)d_in[6];
  const float* ar0  = (const float*)d_in[7];
  const float* Wf   = (const float*)d_in[8];
  const float* alf  = (const float*)d_in[9];
  const float* arf  = (const float*)d_in[10];
  const float* W1   = (const float*)d_in[11];
  const float* b1   = (const float*)d_in[12];
  const float* W2   = (const float*)d_in[13];
  const float* b2   = (const float*)d_in[14];
  float* out = (float*)d_out;

  char* W = (char*)d_ws;
  ushort_t* ftS  = (ushort_t*)(W);              // 3145728 B
  ushort_t* ftfS = (ushort_t*)(W + 3145728);    // 1572864 B
  float* a1arr = (float*)(W + 4718592);         // 98304 B
  float* a2arr = (float*)(W + 4816896);         // 98304 B
  float* a1f   = (float*)(W + 4915200);         // 24576 B
  float* a2f   = (float*)(W + 4939776);         // 24576 B
  float* pmax0 = (float*)(W + 4964352);         // 6144 B
  float* pmaxf = (float*)(W + 4970496);         // 1536 B
  float* ppart = (float*)(W + 4972032);         // 196608 B
  int*   cnt   = (int*)  (W + 5168640);         // 48 B

  hipLaunchKernelGGL(k_f1,       dim3(Nn/16), dim3(256), 0, stream,
                     x, Wv, bv, W0, al0, ar0, ftS, a1arr, a2arr, pmax0, cnt);
  hipLaunchKernelGGL(k_attn0fcf, dim3(NG*32), dim3(512), 0, stream,
                     ftS, a1arr, a2arr, pmax0, mask, Wf, alf, arf, ftfS, a1f, a2f, pmaxf);
  hipLaunchKernelGGL(k_attnf,    dim3(NG*32), dim3(256), 0, stream,
                     ftfS, a1f, a2f, pmaxf, mask, W1, b1, W2, b2, ppart, cnt, out);
}

// Round 11
// 54.988 us; speedup vs baseline: 1.4405x; 1.4405x over previous
//
#include <hip/hip_runtime.h>
#include <math.h>

#define Nn 6144
#define FIN 128
#define DMID 128
#define DHID 64
#define NH 4
#define NG 12
#define NB 512
#define ALPHA 0.2f
#define EPSV 1e-9f

typedef __bf16 bf16x8 __attribute__((ext_vector_type(8)));
typedef float f32x4 __attribute__((ext_vector_type(4)));
typedef unsigned short ushort_t;

union BU { bf16x8 v; uint u[4]; uint4 q; };

__device__ __forceinline__ float leaky(float x){ return x > 0.f ? x : ALPHA*x; }
__device__ __forceinline__ float eluf(float x){ return x > 0.f ? x : __expf(x)-1.f; }
__device__ __forceinline__ uint f2bf(float f){
  uint u = __float_as_uint(f);
  return (u + 0x7FFFu + ((u>>16)&1u)) >> 16;
}
__device__ __forceinline__ float wave_max(float v){
  #pragma unroll
  for (int off=32; off; off>>=1) v = fmaxf(v, __shfl_xor(v, off));
  return v;
}
// pack 8 consecutive-k weights W[k0..k0+7][col] (row stride strd) into one B-frag uint4
__device__ __forceinline__ uint4 packW(const float* p, int strd){
  uint4 pk;
  pk.x = f2bf(p[0])      | (f2bf(p[strd])<<16);
  pk.y = f2bf(p[2*strd]) | (f2bf(p[3*strd])<<16);
  pk.z = f2bf(p[4*strd]) | (f2bf(p[5*strd])<<16);
  pk.w = f2bf(p[6*strd]) | (f2bf(p[7*strd])<<16);
  return pk;
}

// ---------- K1: fc1 + ft0 (MFMA, inline weight fragments) + dots + swizzled ftS ----------
// 384 blocks x 256 threads; block b: rows [b*16, b*16+16)
// blocks 0-7 additionally prepack WfS (consumed by the NEXT dispatch - stream-order safe)
__global__ __launch_bounds__(256) void k_f1(
    const float* __restrict__ x, const float* __restrict__ Wv, const float* __restrict__ bv,
    const float* __restrict__ W0, const float* __restrict__ al0, const float* __restrict__ ar0,
    const float* __restrict__ Wf, ushort_t* __restrict__ WfS,
    ushort_t* __restrict__ ftS, float* __restrict__ a1arr, float* __restrict__ a2arr,
    float* __restrict__ pmax0){
  int b = blockIdx.x; int i0 = b*16;
  int t = threadIdx.x, lane = t&63, w = t>>6;
  int row = lane&15, kg = lane>>4;
  // prepack WfS: 4096 fragment-slots of 16B; blocks 0-7 x 512 slots... 256 thr -> 2 slots each
  if (b < 8){
    #pragma unroll
    for (int e=0; e<2; ++e){
      int s = b*512 + e*256 + t;          // 4096 slots
      int fb = s>>6, ln = s&63;
      int nt = fb>>3, kt = fb&7;
      int col = nt*16 + (ln&15), k0 = kt*32 + (ln>>4)*8;
      *reinterpret_cast<uint4*>(WfS + (size_t)s*8) = packW(Wf + (size_t)k0*DMID + col, DMID);
    }
  }
  __shared__ ushort_t xs[16][136];
  __shared__ ushort_t hts[16][136];
  __shared__ ushort_t fts[16][264];
  {
    const float* xp = x + (size_t)i0*FIN + t*8;
    float4 f0 = *reinterpret_cast<const float4*>(xp);
    float4 f1 = *reinterpret_cast<const float4*>(xp+4);
    uint4 pk;
    pk.x = f2bf(f0.x)|(f2bf(f0.y)<<16); pk.y = f2bf(f0.z)|(f2bf(f0.w)<<16);
    pk.z = f2bf(f1.x)|(f2bf(f1.y)<<16); pk.w = f2bf(f1.z)|(f2bf(f1.w)<<16);
    *reinterpret_cast<uint4*>(&xs[t>>4][(t&15)*8]) = pk;
  }
  __syncthreads();
  // fc1: h = relu(x@Wv+bv); wave w -> n-tiles 2w, 2w+1
  {
    f32x4 acc2[2] = {{0,0,0,0},{0,0,0,0}};
    #pragma unroll
    for (int kt=0; kt<4; ++kt){
      bf16x8 aF = *reinterpret_cast<bf16x8*>(&xs[row][kt*32 + kg*8]);
      #pragma unroll
      for (int e2=0; e2<2; ++e2){
        int nt = w*2+e2;
        BU B;
        B.q = packW(Wv + (size_t)(kt*32 + (lane>>4)*8)*DMID + nt*16 + (lane&15), DMID);
        acc2[e2] = __builtin_amdgcn_mfma_f32_16x16x32_bf16(aF, B.v, acc2[e2], 0, 0, 0);
      }
    }
    #pragma unroll
    for (int e2=0; e2<2; ++e2){
      int nt = w*2+e2;
      float bvv = bv[nt*16+row];
      #pragma unroll
      for (int reg=0; reg<4; ++reg){
        float v = fmaxf(acc2[e2][reg]+bvv, 0.f);
        hts[kg*4+reg][nt*16+row] = (ushort_t)f2bf(v);
      }
    }
  }
  __syncthreads();
  // ft0: head = w; n-tiles 0..3 within head
  f32x4 acc4[4] = {{0,0,0,0},{0,0,0,0},{0,0,0,0},{0,0,0,0}};
  #pragma unroll
  for (int kt=0; kt<4; ++kt){
    bf16x8 aF = *reinterpret_cast<bf16x8*>(&hts[row][kt*32 + kg*8]);
    #pragma unroll
    for (int nt=0; nt<4; ++nt){
      BU B;
      B.q = packW(W0 + (size_t)w*DMID*DHID + (size_t)(kt*32 + (lane>>4)*8)*DHID
                     + nt*16 + (lane&15), DHID);
      acc4[nt] = __builtin_amdgcn_mfma_f32_16x16x32_bf16(aF, B.v, acc4[nt], 0, 0, 0);
    }
  }
  // dots on C-fragments
  {
    float alv[4], arv[4];
    #pragma unroll
    for (int nt=0; nt<4; ++nt){ alv[nt] = al0[w*DHID+nt*16+row]; arv[nt] = ar0[w*DHID+nt*16+row]; }
    float s1[4]={0,0,0,0}, s2[4]={0,0,0,0};
    #pragma unroll
    for (int nt=0; nt<4; ++nt)
      #pragma unroll
      for (int reg=0; reg<4; ++reg){
        s1[reg] += acc4[nt][reg]*alv[nt];
        s2[reg] += acc4[nt][reg]*arv[nt];
      }
    #pragma unroll
    for (int off=1; off<16; off<<=1)
      #pragma unroll
      for (int reg=0; reg<4; ++reg){
        s1[reg] += __shfl_xor(s1[reg], off);
        s2[reg] += __shfl_xor(s2[reg], off);
      }
    if (row==0){
      #pragma unroll
      for (int reg=0; reg<4; ++reg){
        a1arr[w*Nn + i0 + kg*4+reg] = s1[reg];
        a2arr[w*Nn + i0 + kg*4+reg] = s2[reg];
      }
    }
    float mm = fmaxf(fmaxf(s2[0],s2[1]), fmaxf(s2[2],s2[3]));
    mm = fmaxf(mm, __shfl_xor(mm,16));
    mm = fmaxf(mm, __shfl_xor(mm,32));
    if (lane==0) pmax0[w*384 + b] = mm;
  }
  // fts LDS
  #pragma unroll
  for (int nt=0; nt<4; ++nt)
    #pragma unroll
    for (int reg=0; reg<4; ++reg)
      fts[kg*4+reg][w*DHID + nt*16+row] = (ushort_t)f2bf(acc4[nt][reg]);
  __syncthreads();
  // write swizzled ftS: thread t <-> channel
  {
    int ch = t, hd2 = ch>>6, ct = (ch>>4)&3, c = ch&15;
    int g = b>>5, ktj = (b&31)>>1, half = b&1;
    ushort_t v[16];
    #pragma unroll
    for (int i=0; i<16; ++i) v[i] = fts[i][ch];
    uint4 p0, p1;
    p0.x=(uint)v[0]|((uint)v[1]<<16);  p0.y=(uint)v[2]|((uint)v[3]<<16);
    p0.z=(uint)v[4]|((uint)v[5]<<16);  p0.w=(uint)v[6]|((uint)v[7]<<16);
    p1.x=(uint)v[8]|((uint)v[9]<<16);  p1.y=(uint)v[10]|((uint)v[11]<<16);
    p1.z=(uint)v[12]|((uint)v[13]<<16);p1.w=(uint)v[14]|((uint)v[15]<<16);
    size_t base = (((size_t)(g*4+hd2)*16 + ktj)*4 + ct)*512;
    *reinterpret_cast<uint4*>(ftS + base + ((half*2+0)*16+c)*8) = p0;
    *reinterpret_cast<uint4*>(ftS + base + ((half*2+1)*16+c)*8) = p1;
  }
}

// ---------- K2: fused attention-0 (4 heads x 2 j-halves) + fcf (prepacked WfS) ----------
__global__ __launch_bounds__(512) void k_attn0fcf(
    const ushort_t* __restrict__ ftS, const float* __restrict__ a1arr,
    const float* __restrict__ a2arr, const float* __restrict__ pmax0,
    const float* __restrict__ mask, const ushort_t* __restrict__ WfS,
    const float* __restrict__ alf, const float* __restrict__ arf,
    ushort_t* __restrict__ ftfS, float* __restrict__ a1f, float* __restrict__ a2f,
    float* __restrict__ pmaxf){
  int b = blockIdx.x;            // 384 = g*32 + it
  int g = b>>5, it = b&31;
  int i0 = g*NB + it*16, jbase = g*NB;
  int t = threadIdx.x, lane = t&63, w = t>>6;
  int hd = w>>1, jh = w&1;
  int row = lane&15, kg = lane>>4;

  __shared__ float aacc[8][4][64][4];    // 32 KB
  __shared__ float ad[8][16];
  __shared__ ushort_t h1s[16][264];      // 8.4 KB
  __shared__ ushort_t fts[16][136];      // 4.3 KB
  __shared__ float dpA[8][16], dpB[8][16];

  // ---- phase A: scores + PV (head hd, j-half jh) ----
  {
    float mxv = -INFINITY;
    #pragma unroll
    for (int q=0; q<6; ++q) mxv = fmaxf(mxv, pmax0[hd*384 + q*64 + lane]);
    mxv = wave_max(mxv);
    float a1v = a1arr[hd*Nn + i0 + row];
    float mv = leaky(a1v + mxv);
    f32x4 acc[4] = {{0,0,0,0},{0,0,0,0},{0,0,0,0},{0,0,0,0}};
    float dsum = 0.f;
    const float* mrow = mask + (size_t)(i0+row)*Nn;
    size_t fbase = ((size_t)(g*4+hd)*16*4)*512;
    #pragma unroll 2
    for (int c8=0; c8<8; ++c8){
      int kt = jh*8 + c8;
      int jc = jbase + kt*32 + kg*8;
      float4 mk0 = *reinterpret_cast<const float4*>(mrow + jc);
      float4 mk1 = *reinterpret_cast<const float4*>(mrow + jc + 4);
      float4 a20 = *reinterpret_cast<const float4*>(a2arr + hd*Nn + jc);
      float4 a21 = *reinterpret_cast<const float4*>(a2arr + hd*Nn + jc + 4);
      float a2l[8] = {a20.x,a20.y,a20.z,a20.w,a21.x,a21.y,a21.z,a21.w};
      float mkl[8] = {mk0.x,mk0.y,mk0.z,mk0.w,mk1.x,mk1.y,mk1.z,mk1.w};
      float wv[8];
      #pragma unroll
      for (int e=0;e<8;++e){
        float p = __expf(leaky(a1v + a2l[e]) - mv) * mkl[e];
        wv[e] = p; dsum += p;
      }
      BU A;
      #pragma unroll
      for (int q=0;q<4;++q) A.u[q] = f2bf(wv[2*q]) | (f2bf(wv[2*q+1])<<16);
      #pragma unroll
      for (int ct=0; ct<4; ++ct){
        BU B; B.q = *reinterpret_cast<const uint4*>(ftS + fbase + (size_t)(kt*4+ct)*512 + lane*8);
        acc[ct] = __builtin_amdgcn_mfma_f32_16x16x32_bf16(A.v, B.v, acc[ct], 0, 0, 0);
      }
    }
    dsum += __shfl_xor(dsum, 16);
    dsum += __shfl_xor(dsum, 32);
    if (lane < 16) ad[w][lane] = dsum;
    #pragma unroll
    for (int ct=0; ct<4; ++ct)
      *reinterpret_cast<float4*>(&aacc[w][ct][lane][0]) = (float4){acc[ct][0],acc[ct][1],acc[ct][2],acc[ct][3]};
  }
  __syncthreads();
  // ---- phase B: combine j-halves, ELU, write h1 tile (bf16 LDS) ----
  {
    int w0 = hd*2, w1 = hd*2+1;
    float dr[4];
    #pragma unroll
    for (int reg=0; reg<4; ++reg) dr[reg] = ad[w0][kg*4+reg] + ad[w1][kg*4+reg] + EPSV;
    #pragma unroll
    for (int ci=0; ci<2; ++ci){
      int ct = jh*2+ci;
      float4 A0 = *reinterpret_cast<float4*>(&aacc[w0][ct][lane][0]);
      float4 A1 = *reinterpret_cast<float4*>(&aacc[w1][ct][lane][0]);
      float tot[4] = {A0.x+A1.x, A0.y+A1.y, A0.z+A1.z, A0.w+A1.w};
      #pragma unroll
      for (int reg=0; reg<4; ++reg){
        float o = eluf(tot[reg]/dr[reg]);
        h1s[kg*4+reg][hd*64 + ct*16 + row] = (ushort_t)f2bf(o);
      }
    }
  }
  __syncthreads();
  // ---- phase C: fcf (wave w -> n-tile w), prepacked WfS fragments, dots ----
  {
    f32x4 acc2 = {0,0,0,0};
    #pragma unroll
    for (int kt=0; kt<8; ++kt){
      bf16x8 aF = *reinterpret_cast<bf16x8*>(&h1s[row][kt*32 + kg*8]);
      BU B; B.q = *reinterpret_cast<const uint4*>(WfS + ((size_t)(w*8+kt)*64 + lane)*8);
      acc2 = __builtin_amdgcn_mfma_f32_16x16x32_bf16(aF, B.v, acc2, 0, 0, 0);
    }
    float alv = alf[w*16+row], arv = arf[w*16+row];
    float s1[4], s2[4];
    #pragma unroll
    for (int reg=0; reg<4; ++reg){
      s1[reg] = acc2[reg]*alv;
      s2[reg] = acc2[reg]*arv;
      fts[kg*4+reg][w*16+row] = (ushort_t)f2bf(acc2[reg]);
    }
    #pragma unroll
    for (int off=1; off<16; off<<=1)
      #pragma unroll
      for (int reg=0; reg<4; ++reg){
        s1[reg] += __shfl_xor(s1[reg], off);
        s2[reg] += __shfl_xor(s2[reg], off);
      }
    if (row==0){
      #pragma unroll
      for (int reg=0; reg<4; ++reg){ dpA[w][kg*4+reg]=s1[reg]; dpB[w][kg*4+reg]=s2[reg]; }
    }
  }
  __syncthreads();
  if (t < 16){
    float v1=0.f, v2=0.f;
    #pragma unroll
    for (int q=0; q<8; ++q){ v1 += dpA[q][t]; v2 += dpB[q][t]; }
    a1f[i0+t] = v1; a2f[i0+t] = v2;
    float m = v2;
    #pragma unroll
    for (int off=1; off<16; off<<=1) m = fmaxf(m, __shfl_xor(m, off));
    if (t==0) pmaxf[b] = m;
  }
  // ---- swizzled ftfS write (first 256 threads) ----
  if (t < 256){
    int ch = t>>1, half8 = t&1;
    int ct = ch>>4, c = ch&15;
    int gg = b>>5, ktj = (b&31)>>1, half = b&1;
    ushort_t v[8];
    #pragma unroll
    for (int i=0; i<8; ++i) v[i] = fts[half8*8+i][ch];
    uint4 pk;
    pk.x=(uint)v[0]|((uint)v[1]<<16); pk.y=(uint)v[2]|((uint)v[3]<<16);
    pk.z=(uint)v[4]|((uint)v[5]<<16); pk.w=(uint)v[6]|((uint)v[7]<<16);
    int kslot = half*2 + half8;
    size_t base = ((size_t)(gg*16+ktj)*8 + ct)*512;
    *reinterpret_cast<uint4*>(ftfS + base + (kslot*16+c)*8) = pk;
  }
}

// ---------- K3: final attention (MFMA, 4-way j-split) + pool partials ----------
__global__ __launch_bounds__(256) void k_attnf(
    const ushort_t* __restrict__ ftfS, const float* __restrict__ a1f,
    const float* __restrict__ a2f, const float* __restrict__ pmaxf,
    const float* __restrict__ mask, float* __restrict__ ppart){
  int b = blockIdx.x;             // 384: g, it
  int g = b>>5, it = b&31;
  int i0 = g*NB + it*16, jbase = g*NB;
  int t = threadIdx.x, lane = t&63, w = t>>6;
  int row = lane&15, kg = lane>>4;
  __shared__ float s_acc[4][8][64][4];   // 32 KB
  __shared__ float s_d[4][16];
  float mxv = -INFINITY;
  #pragma unroll
  for (int q=0; q<6; ++q) mxv = fmaxf(mxv, pmaxf[q*64 + lane]);
  mxv = wave_max(mxv);
  float a1v = a1f[i0+row];
  float mv = leaky(a1v + mxv);
  f32x4 acc[8];
  #pragma unroll
  for (int ct=0; ct<8; ++ct) acc[ct] = (f32x4){0,0,0,0};
  float dsum = 0.f;
  const float* mrow = mask + (size_t)(i0+row)*Nn;
  #pragma unroll 2
  for (int c4=0; c4<4; ++c4){
    int kt = w*4 + c4;
    int jc = jbase + kt*32 + kg*8;
    float4 mk0 = *reinterpret_cast<const float4*>(mrow + jc);
    float4 mk1 = *reinterpret_cast<const float4*>(mrow + jc + 4);
    float4 a20 = *reinterpret_cast<const float4*>(a2f + jc);
    float4 a21 = *reinterpret_cast<const float4*>(a2f + jc + 4);
    float a2l[8] = {a20.x,a20.y,a20.z,a20.w,a21.x,a21.y,a21.z,a21.w};
    float mkl[8] = {mk0.x,mk0.y,mk0.z,mk0.w,mk1.x,mk1.y,mk1.z,mk1.w};
    float wv[8];
    #pragma unroll
    for (int e=0;e<8;++e){
      float p = __expf(leaky(a1v + a2l[e]) - mv) * mkl[e];
      wv[e] = p; dsum += p;
    }
    BU A;
    #pragma unroll
    for (int q=0;q<4;++q) A.u[q] = f2bf(wv[2*q]) | (f2bf(wv[2*q+1])<<16);
    #pragma unroll
    for (int ct=0; ct<8; ++ct){
      BU B; B.q = *reinterpret_cast<const uint4*>(ftfS + ((size_t)(g*16+kt)*8 + ct)*512 + lane*8);
      acc[ct] = __builtin_amdgcn_mfma_f32_16x16x32_bf16(A.v, B.v, acc[ct], 0, 0, 0);
    }
  }
  dsum += __shfl_xor(dsum, 16);
  dsum += __shfl_xor(dsum, 32);
  if (lane < 16) s_d[w][lane] = dsum;
  #pragma unroll
  for (int ct=0; ct<8; ++ct)
    *reinterpret_cast<float4*>(&s_acc[w][ct][lane][0]) = (float4){acc[ct][0],acc[ct][1],acc[ct][2],acc[ct][3]};
  __syncthreads();
  float dr[4];
  #pragma unroll
  for (int reg=0; reg<4; ++reg)
    dr[reg] = s_d[0][kg*4+reg] + s_d[1][kg*4+reg] + s_d[2][kg*4+reg] + s_d[3][kg*4+reg] + EPSV;
  #pragma unroll
  for (int ci=0; ci<2; ++ci){
    int ct = w*2 + ci;
    float4 A0 = *reinterpret_cast<float4*>(&s_acc[0][ct][lane][0]);
    float4 A1 = *reinterpret_cast<float4*>(&s_acc[1][ct][lane][0]);
    float4 A2 = *reinterpret_cast<float4*>(&s_acc[2][ct][lane][0]);
    float4 A3 = *reinterpret_cast<float4*>(&s_acc[3][ct][lane][0]);
    float tot[4] = {A0.x+A1.x+A2.x+A3.x, A0.y+A1.y+A2.y+A3.y,
                    A0.z+A1.z+A2.z+A3.z, A0.w+A1.w+A2.w+A3.w};
    float psum = 0.f;
    #pragma unroll
    for (int reg=0; reg<4; ++reg) psum += eluf(tot[reg]/dr[reg]);
    psum += __shfl_xor(psum, 16);
    psum += __shfl_xor(psum, 32);
    if (lane < 16) ppart[(size_t)b*DMID + ct*16 + lane] = psum;
  }
}

// ---------- K4: reduce ppart + MLP ----------
__global__ __launch_bounds__(256) void k_mlp(
    const float* __restrict__ ppart, const float* __restrict__ W1, const float* __restrict__ b1,
    const float* __restrict__ W2, const float* __restrict__ b2, float* __restrict__ out){
  int g = blockIdx.x;
  int t = threadIdx.x;
  __shared__ float red[8][DMID];
  __shared__ float ps[DMID], ts[DMID];
  __shared__ float p2[2][DMID];
  __shared__ float p4[2][16];
  {
    float4 s4 = {0,0,0,0};
    #pragma unroll
    for (int gi=0; gi<4; ++gi){
      int itx = (t>>5) + gi*8;
      float4 v = *reinterpret_cast<const float4*>(ppart + (size_t)(g*32+itx)*DMID + (t&31)*4);
      s4.x += v.x; s4.y += v.y; s4.z += v.z; s4.w += v.w;
    }
    *reinterpret_cast<float4*>(&red[t>>5][(t&31)*4]) = s4;
  }
  __syncthreads();
  if (t < DMID){
    float s = 0.f;
    #pragma unroll
    for (int q=0; q<8; ++q) s += red[q][t];
    ps[t] = s;
  }
  __syncthreads();
  {
    int col = t & 127, half = t>>7;
    float acc = 0.f;
    #pragma unroll 8
    for (int k=half*64; k<half*64+64; ++k) acc += ps[k]*W1[k*DMID+col];
    p2[half][col] = acc;
  }
  __syncthreads();
  if (t < DMID) ts[t] = fmaxf(p2[0][t]+p2[1][t]+b1[t], 0.f);
  __syncthreads();
  if (t < 32){
    int col = t & 15, half = t>>4;
    float acc = 0.f;
    #pragma unroll 8
    for (int k=half*64; k<half*64+64; ++k) acc += ts[k]*W2[k*16+col];
    p4[half][col] = acc;
  }
  __syncthreads();
  if (t < 16) out[g*16+t] = p4[0][t]+p4[1][t]+b2[t];
}

extern "C" void kernel_launch(void* const* d_in, const int* in_sizes, int n_in,
                              void* d_out, int out_size, void* d_ws, size_t ws_size,
                              hipStream_t stream) {
  const float* x    = (const float*)d_in[0];
  const float* mask = (const float*)d_in[1];
  const float* Wv   = (const float*)d_in[3];
  const float* bv   = (const float*)d_in[4];
  const float* W0   = (const float*)d_in[5];
  const float* al0  = (const float*)d_in[6];
  const float* ar0  = (const float*)d_in[7];
  const float* Wf   = (const float*)d_in[8];
  const float* alf  = (const float*)d_in[9];
  const float* arf  = (const float*)d_in[10];
  const float* W1   = (const float*)d_in[11];
  const float* b1   = (const float*)d_in[12];
  const float* W2   = (const float*)d_in[13];
  const float* b2   = (const float*)d_in[14];
  float* out = (float*)d_out;

  char* W = (char*)d_ws;
  ushort_t* ftS  = (ushort_t*)(W);              // 3145728 B
  ushort_t* ftfS = (ushort_t*)(W + 3145728);    // 1572864 B
  ushort_t* WfS  = (ushort_t*)(W + 4718592);    // 65536 B
  float* a1arr = (float*)(W + 4784128);         // 98304 B
  float* a2arr = (float*)(W + 4882432);         // 98304 B
  float* a1f   = (float*)(W + 4980736);         // 24576 B
  float* a2f   = (float*)(W + 5005312);         // 24576 B
  float* pmax0 = (float*)(W + 5029888);         // 6144 B
  float* pmaxf = (float*)(W + 5036032);         // 1536 B
  float* ppart = (float*)(W + 5037568);         // 196608 B

  hipLaunchKernelGGL(k_f1,       dim3(Nn/16), dim3(256), 0, stream,
                     x, Wv, bv, W0, al0, ar0, Wf, WfS, ftS, a1arr, a2arr, pmax0);
  hipLaunchKernelGGL(k_attn0fcf, dim3(NG*32), dim3(512), 0, stream,
                     ftS, a1arr, a2arr, pmax0, mask, WfS, alf, arf, ftfS, a1f, a2f, pmaxf);
  hipLaunchKernelGGL(k_attnf,    dim3(NG*32), dim3(256), 0, stream,
                     ftfS, a1f, a2f, pmaxf, mask, ppart);
  hipLaunchKernelGGL(k_mlp,      dim3(NG),    dim3(256), 0, stream,
                     ppart, W1, b1, W2, b2, out);
}